// Round 3
// baseline (550.258 us; speedup 1.0000x reference)
//
#include <hip/hip_runtime.h>

#define NROWS 32768
#define DDIM  128
#define KCODES 1024
#define DECAY 0.99f
#define OMD   0.01f
#define EPS   1e-5f

// ws layout (floats): [counts 1024][esum 131072][keys u64: 32768*2][en2h 1024][inv 1024]
#define WS_COUNTS 0
#define WS_ESUM   1024
#define WS_KEYS   (1024 + 131072)              // byte offset 528384, 8B aligned
#define WS_EN2H   (WS_KEYS + 65536)
#define WS_INV    (WS_EN2H + 1024)
#define WS_ZERO_FLOATS (WS_KEYS + 65536)       // zero counts+esum+keys in one memset

// ---- K0: half squared norms of codebook rows; one wave per code ----
__global__ void norms_kernel(const float* __restrict__ embed, float* __restrict__ en2h) {
  int w = threadIdx.x >> 6;
  int lane = threadIdx.x & 63;
  int k = blockIdx.x * 4 + w;
  const float2* p = (const float2*)(embed + k * DDIM);
  float2 v = p[lane];
  float s = v.x * v.x + v.y * v.y;
  #pragma unroll
  for (int off = 32; off > 0; off >>= 1) s += __shfl_down(s, off, 64);
  if (lane == 0) en2h[k] = 0.5f * s;
}

// ---- K1: scoring scan. Lane owns one x-row (128 VGPRs); wave scans 128 codes
// with wave-uniform e-loads (scalar pipe). No LDS, no barriers. ----
__global__ __launch_bounds__(256) void vq_scan(
    const float* __restrict__ x, const float* __restrict__ embed,
    const float* __restrict__ en2h, unsigned long long* __restrict__ keys) {
  const int cg = blockIdx.x & 7;                    // code group (8 x 128 codes)
  const int row = (blockIdx.x >> 3) * 256 + threadIdx.x;

  // own row into registers (32 float4 = 128 VGPRs)
  float4 xr[32];
  const float4* xp = (const float4*)(x + (size_t)row * DDIM);
  #pragma unroll
  for (int i = 0; i < 32; ++i) xr[i] = xp[i];

  const float* eb = embed + (size_t)(cg << 7) * DDIM;
  const float* nh = en2h + (cg << 7);

  float bestv = -3.4e38f;
  int besti = 0;
  for (int k = 0; k < 128; ++k) {
    const float* ek = eb + (k << 7);                // uniform address -> s_load
    float a0 = 0.f, a1 = 0.f, a2 = 0.f, a3 = 0.f;  // ILP-4 accumulators
    #pragma unroll
    for (int d = 0; d < 32; ++d) {
      a0 += xr[d].x * ek[4 * d + 0];
      a1 += xr[d].y * ek[4 * d + 1];
      a2 += xr[d].z * ek[4 * d + 2];
      a3 += xr[d].w * ek[4 * d + 3];
    }
    float s = ((a0 + a1) + (a2 + a3)) - nh[k];      // score = x.e - 0.5|e|^2
    if (s > bestv) { bestv = s; besti = (cg << 7) + k; }  // strict >: first max
  }

  // pack (score, idx) -> monotonic u64; ~idx so equal scores pick LOWEST idx
  unsigned u = __float_as_uint(bestv);
  unsigned su = (u & 0x80000000u) ? ~u : (u | 0x80000000u);
  unsigned long long key =
      ((unsigned long long)su << 32) | (unsigned long long)(0xFFFFFFFFu - (unsigned)besti);
  atomicMax(keys + row, key);
}

// ---- K2: extract argmax, write embed_ind, count ----
__global__ void post1(const unsigned long long* __restrict__ keys,
                      float* __restrict__ counts, float* __restrict__ out_ind) {
  int row = blockIdx.x * 256 + threadIdx.x;
  unsigned long long k = keys[row];
  int code = (int)(0xFFFFFFFFu - (unsigned)(k & 0xFFFFFFFFull));
  out_ind[row] = (float)code;
  unsafeAtomicAdd(counts + code, 1.0f);   // native global_atomic_add_f32
}

// ---- K3: quantize gather-write + embed_sum scatter (coalesced, native fadd) ----
__global__ void post2(const unsigned long long* __restrict__ keys,
                      const float* __restrict__ x, const float* __restrict__ embed,
                      float* __restrict__ esum, float* __restrict__ out_q) {
  int gid = blockIdx.x * 256 + threadIdx.x;         // 0 .. 1048575 (x4 elems)
  int row = gid >> 5, c4 = gid & 31;
  unsigned long long k = keys[row];
  int code = (int)(0xFFFFFFFFu - (unsigned)(k & 0xFFFFFFFFull));
  float4 e = *(const float4*)(embed + code * DDIM + c4 * 4);
  *(float4*)(out_q + (size_t)gid * 4) = e;
  float4 xv = *(const float4*)(x + (size_t)gid * 4);
  float* ep = esum + code * DDIM + c4 * 4;
  unsafeAtomicAdd(ep + 0, xv.x);
  unsafeAtomicAdd(ep + 1, xv.y);
  unsafeAtomicAdd(ep + 2, xv.z);
  unsafeAtomicAdd(ep + 3, xv.w);
}

// ---- K4: new_cluster_size, total, inverse smoothed ----
__global__ void fin1(const float* __restrict__ counts, const float* __restrict__ cs,
                     float* __restrict__ out_ncs, float* __restrict__ inv) {
  __shared__ float wsum[16];
  int tid = threadIdx.x;
  int lane = tid & 63, w = tid >> 6;
  float ncs = cs[tid] * DECAY + OMD * counts[tid];
  out_ncs[tid] = ncs;
  float s = ncs;
  #pragma unroll
  for (int off = 32; off > 0; off >>= 1) s += __shfl_down(s, off, 64);
  if (lane == 0) wsum[w] = s;
  __syncthreads();
  if (tid == 0) {
    float t = 0.f;
    #pragma unroll
    for (int i = 0; i < 16; ++i) t += wsum[i];
    wsum[0] = t;
  }
  __syncthreads();
  float total = wsum[0];
  inv[tid] = (total + (float)KCODES * EPS) / ((ncs + EPS) * total);
}

// ---- K5: new_embed_avg + new_embed ----
__global__ void fin2(const float* __restrict__ ea, const float* __restrict__ esum,
                     const float* __restrict__ inv,
                     float* __restrict__ out_nea, float* __restrict__ out_ne) {
  int gid = blockIdx.x * 256 + threadIdx.x;  // 0..32767, 4 elems each
  int base = gid * 4;
  int k = base >> 7;
  float4 a = *(const float4*)(ea + base);
  float4 s = *(const float4*)(esum + base);
  float iv = inv[k];
  float4 nea;
  nea.x = a.x * DECAY + OMD * s.x; nea.y = a.y * DECAY + OMD * s.y;
  nea.z = a.z * DECAY + OMD * s.z; nea.w = a.w * DECAY + OMD * s.w;
  *(float4*)(out_nea + base) = nea;
  float4 ne;
  ne.x = nea.x * iv; ne.y = nea.y * iv; ne.z = nea.z * iv; ne.w = nea.w * iv;
  *(float4*)(out_ne + base) = ne;
}

extern "C" void kernel_launch(void* const* d_in, const int* in_sizes, int n_in,
                              void* d_out, int out_size, void* d_ws, size_t ws_size,
                              hipStream_t stream) {
  const float* x     = (const float*)d_in[0];
  const float* embed = (const float*)d_in[1];
  const float* cs    = (const float*)d_in[2];
  const float* ea    = (const float*)d_in[3];

  float* out     = (float*)d_out;
  float* out_q   = out;                       // 4194304
  float* out_ind = out_q + 4194304;           // 32768
  float* out_ncs = out_ind + 32768;           // 1024
  float* out_nea = out_ncs + 1024;            // 131072
  float* out_ne  = out_nea + 131072;          // 131072

  float* ws     = (float*)d_ws;
  float* counts = ws + WS_COUNTS;
  float* esum   = ws + WS_ESUM;
  unsigned long long* keys = (unsigned long long*)(ws + WS_KEYS);
  float* en2h   = ws + WS_EN2H;
  float* inv    = ws + WS_INV;

  hipMemsetAsync(ws, 0, (size_t)WS_ZERO_FLOATS * sizeof(float), stream);
  norms_kernel<<<KCODES / 4, 256, 0, stream>>>(embed, en2h);
  vq_scan<<<(NROWS / 256) * 8, 256, 0, stream>>>(x, embed, en2h, keys);
  post1<<<NROWS / 256, 256, 0, stream>>>(keys, counts, out_ind);
  post2<<<(NROWS * 32) / 256, 256, 0, stream>>>(keys, x, embed, esum, out_q);
  fin1<<<1, 1024, 0, stream>>>(counts, cs, out_ncs, inv);
  fin2<<<NROWS / 256, 256, 0, stream>>>(ea, esum, inv, out_nea, out_ne);
}